// Round 1
// baseline (2878.050 us; speedup 1.0000x reference)
//
#include <hip/hip_runtime.h>
#include <hip/hip_bf16.h>

#define TT    2048
#define BATCH 64
#define IDIM  128
#define HDIM  256
#define ODIM  512
#define M1    (BATCH * TT)   // 131072 rows

typedef __bf16 bf16x4 __attribute__((ext_vector_type(4)));
typedef __bf16 bf16x8 __attribute__((ext_vector_type(8)));
typedef float  f32x4  __attribute__((ext_vector_type(4)));

// ---------------------------------------------------------------------------
// GEMM (B-transposed weights): C[m][n] = sum_k A[m][k] * Bw[n][k] + bias[n]
// BM rows per block, BN = NW*64 = full N covered by NW waves, BK = 32 K-step.
// bf16 MFMA 16x16x32; A,B staged f32->bf16 into LDS.
// ---------------------------------------------------------------------------
template<int BM, int NW, int N, int K>
__global__ __launch_bounds__(NW * 64)
void gemm_bt(const float* __restrict__ A, const float* __restrict__ Bw,
             const float* __restrict__ bias, float* __restrict__ C)
{
    constexpr int BN = NW * 64;
    constexpr int BK = 32;
    constexpr int PK = BK + 8;            // row stride 40 shorts = 80 B (16B mult.)
    constexpr int MF = BM / 16;           // m-fragments per wave
    __shared__ __bf16 As[BM][PK];
    __shared__ __bf16 Bs[BN][PK];

    const int tid  = threadIdx.x;
    const int lane = tid & 63;
    const int wave = tid >> 6;
    const int l15  = lane & 15;
    const int l4   = lane >> 4;
    const long mrow = (long)blockIdx.x * BM;

    f32x4 acc[MF][4];
#pragma unroll
    for (int i = 0; i < MF; ++i)
#pragma unroll
        for (int j = 0; j < 4; ++j) acc[i][j] = (f32x4){0.f, 0.f, 0.f, 0.f};

    constexpr int THR   = NW * 64;
    constexpr int A_IT  = (BM * BK) / (THR * 4);
    constexpr int B_IT  = (BN * BK) / (THR * 4);
    static_assert(A_IT * THR * 4 == BM * BK, "A staging mismatch");
    static_assert(B_IT * THR * 4 == BN * BK, "B staging mismatch");

    for (int k0 = 0; k0 < K; k0 += BK) {
#pragma unroll
        for (int it = 0; it < A_IT; ++it) {
            int e = tid * 4 + it * THR * 4;
            int r = e / BK, c = e % BK;
            float4 v = *(const float4*)(A + (mrow + r) * K + (k0 + c));
            bf16x4 p = {(__bf16)v.x, (__bf16)v.y, (__bf16)v.z, (__bf16)v.w};
            *(bf16x4*)&As[r][c] = p;
        }
#pragma unroll
        for (int it = 0; it < B_IT; ++it) {
            int e = tid * 4 + it * THR * 4;
            int r = e / BK, c = e % BK;
            float4 v = *(const float4*)(Bw + (long)r * K + (k0 + c));
            bf16x4 p = {(__bf16)v.x, (__bf16)v.y, (__bf16)v.z, (__bf16)v.w};
            *(bf16x4*)&Bs[r][c] = p;
        }
        __syncthreads();

        const int kk = l4 * 8;            // k-offset within BK=32
        bf16x8 a[MF], b[4];
#pragma unroll
        for (int mf = 0; mf < MF; ++mf)
            a[mf] = *(const bf16x8*)&As[mf * 16 + l15][kk];
#pragma unroll
        for (int nf = 0; nf < 4; ++nf)
            b[nf] = *(const bf16x8*)&Bs[wave * 64 + nf * 16 + l15][kk];
#pragma unroll
        for (int mf = 0; mf < MF; ++mf)
#pragma unroll
            for (int nf = 0; nf < 4; ++nf)
                acc[mf][nf] = __builtin_amdgcn_mfma_f32_16x16x32_bf16(
                    a[mf], b[nf], acc[mf][nf], 0, 0, 0);
        __syncthreads();
    }

    // epilogue: D row = (lane>>4)*4 + j, col = lane&15 (HW-verified layout)
#pragma unroll
    for (int nf = 0; nf < 4; ++nf) {
        const int col = wave * 64 + nf * 16 + l15;
        const float bv = bias[col];
#pragma unroll
        for (int mf = 0; mf < MF; ++mf) {
#pragma unroll
            for (int j = 0; j < 4; ++j) {
                long row = mrow + mf * 16 + l4 * 4 + j;
                C[row * N + col] = acc[mf][nf][j] + bv;
            }
        }
    }
}

// ---------------------------------------------------------------------------
// Sequential scan: h <- 0.9 h + 0.1 tanh(xp[t] + W_hh h), write h_all.
// One block per batch element. 512 threads: thread = (g = tid>>1, kb = tid&1).
// W_hh row-half (128 f32) held in registers. h double-buffered in LDS ->
// exactly one __syncthreads per step. k-reduction via __shfl_xor(.,1).
// ---------------------------------------------------------------------------
__global__ __launch_bounds__(512, 2)
void rnn_scan(const float* __restrict__ xp, const float* __restrict__ h0,
              const float* __restrict__ Whh, float* __restrict__ h_all)
{
    __shared__ float hs[2][HDIM];
    const int tid = threadIdx.x;
    const int g   = tid >> 1;   // output index 0..255
    const int kb  = tid & 1;    // k-half 0/1

    float w[128];
#pragma unroll
    for (int j = 0; j < 128; j += 4) {
        float4 v = *(const float4*)(Whh + (long)g * HDIM + kb * 128 + j);
        w[j] = v.x; w[j + 1] = v.y; w[j + 2] = v.z; w[j + 3] = v.w;
    }
    if (tid < HDIM) hs[0][tid] = h0[(long)blockIdx.x * HDIM + tid];
    __syncthreads();

    const long base = (long)blockIdx.x * TT * HDIM;
    for (int t = 0; t < TT; ++t) {
        float xv = xp[base + (long)t * HDIM + g];   // hidden under FMA burst
        const float4* h4 = ((const float4*)hs[t & 1]) + kb * 32;
        float a0 = 0.f, a1 = 0.f, a2 = 0.f, a3 = 0.f;
#pragma unroll
        for (int j = 0; j < 32; ++j) {
            float4 hv = h4[j];
            a0 = fmaf(w[4 * j + 0], hv.x, a0);
            a1 = fmaf(w[4 * j + 1], hv.y, a1);
            a2 = fmaf(w[4 * j + 2], hv.z, a2);
            a3 = fmaf(w[4 * j + 3], hv.w, a3);
        }
        float s = (a0 + a1) + (a2 + a3);
        s += __shfl_xor(s, 1);                      // combine the two k-halves
        float pre = xv + s;
        float th  = 1.f - 2.f / (1.f + __expf(2.f * pre));   // tanh
        float hn  = 0.9f * hs[t & 1][g] + 0.1f * th;
        if (kb == 0) {
            hs[(t + 1) & 1][g] = hn;
            h_all[base + (long)t * HDIM + g] = hn;
        }
        __syncthreads();   // single barrier per step (double-buffered h)
    }
}

// ---------------------------------------------------------------------------
extern "C" void kernel_launch(void* const* d_in, const int* in_sizes, int n_in,
                              void* d_out, int out_size, void* d_ws, size_t ws_size,
                              hipStream_t stream)
{
    const float* x   = (const float*)d_in[0];
    const float* h0  = (const float*)d_in[1];
    const float* Wxh = (const float*)d_in[2];
    const float* bxh = (const float*)d_in[3];
    const float* Whh = (const float*)d_in[4];
    const float* Why = (const float*)d_in[5];
    const float* bhy = (const float*)d_in[6];

    float* y     = (float*)d_out;                 // (M1, 512)
    float* h_all = y + (long)M1 * ODIM;           // (M1, 256)
    float* xp    = y;   // scratch: xp (M1*256 f32) fits in y region; dead before K3

    // K1: xp = x @ Wxh^T + bxh
    gemm_bt<64, 4, HDIM, IDIM><<<M1 / 64, 4 * 64, 0, stream>>>(x, Wxh, bxh, xp);
    // K2: sequential scan -> h_all
    rnn_scan<<<BATCH, 512, 0, stream>>>(xp, h0, Whh, h_all);
    // K3: y = h_all @ Why^T + bhy
    gemm_bt<64, 8, ODIM, HDIM><<<M1 / 64, 8 * 64, 0, stream>>>(h_all, Why, bhy, y);
}

// Round 2
// 1619.962 us; speedup vs baseline: 1.7766x; 1.7766x over previous
//
#include <hip/hip_runtime.h>
#include <hip/hip_bf16.h>

#define TT    2048
#define BATCH 64
#define IDIM  128
#define HDIM  256
#define ODIM  512
#define M1    (BATCH * TT)   // 131072 rows

typedef __bf16 bf16x4 __attribute__((ext_vector_type(4)));
typedef __bf16 bf16x8 __attribute__((ext_vector_type(8)));
typedef float  f32x4  __attribute__((ext_vector_type(4)));
typedef float  f32x2  __attribute__((ext_vector_type(2)));

// ---------------------------------------------------------------------------
// GEMM (B-transposed weights): C[m][n] = sum_k A[m][k] * Bw[n][k] + bias[n]
// (unchanged from R1 — passes, ~145 us combined, not the bottleneck)
// ---------------------------------------------------------------------------
template<int BM, int NW, int N, int K>
__global__ __launch_bounds__(NW * 64)
void gemm_bt(const float* __restrict__ A, const float* __restrict__ Bw,
             const float* __restrict__ bias, float* __restrict__ C)
{
    constexpr int BN = NW * 64;
    constexpr int BK = 32;
    constexpr int PK = BK + 8;
    constexpr int MF = BM / 16;
    __shared__ __bf16 As[BM][PK];
    __shared__ __bf16 Bs[BN][PK];

    const int tid  = threadIdx.x;
    const int lane = tid & 63;
    const int wave = tid >> 6;
    const int l15  = lane & 15;
    const int l4   = lane >> 4;
    const long mrow = (long)blockIdx.x * BM;

    f32x4 acc[MF][4];
#pragma unroll
    for (int i = 0; i < MF; ++i)
#pragma unroll
        for (int j = 0; j < 4; ++j) acc[i][j] = (f32x4){0.f, 0.f, 0.f, 0.f};

    constexpr int THR   = NW * 64;
    constexpr int A_IT  = (BM * BK) / (THR * 4);
    constexpr int B_IT  = (BN * BK) / (THR * 4);

    for (int k0 = 0; k0 < K; k0 += BK) {
#pragma unroll
        for (int it = 0; it < A_IT; ++it) {
            int e = tid * 4 + it * THR * 4;
            int r = e / BK, c = e % BK;
            float4 v = *(const float4*)(A + (mrow + r) * K + (k0 + c));
            bf16x4 p = {(__bf16)v.x, (__bf16)v.y, (__bf16)v.z, (__bf16)v.w};
            *(bf16x4*)&As[r][c] = p;
        }
#pragma unroll
        for (int it = 0; it < B_IT; ++it) {
            int e = tid * 4 + it * THR * 4;
            int r = e / BK, c = e % BK;
            float4 v = *(const float4*)(Bw + (long)r * K + (k0 + c));
            bf16x4 p = {(__bf16)v.x, (__bf16)v.y, (__bf16)v.z, (__bf16)v.w};
            *(bf16x4*)&Bs[r][c] = p;
        }
        __syncthreads();

        const int kk = l4 * 8;
        bf16x8 a[MF], b[4];
#pragma unroll
        for (int mf = 0; mf < MF; ++mf)
            a[mf] = *(const bf16x8*)&As[mf * 16 + l15][kk];
#pragma unroll
        for (int nf = 0; nf < 4; ++nf)
            b[nf] = *(const bf16x8*)&Bs[wave * 64 + nf * 16 + l15][kk];
#pragma unroll
        for (int mf = 0; mf < MF; ++mf)
#pragma unroll
            for (int nf = 0; nf < 4; ++nf)
                acc[mf][nf] = __builtin_amdgcn_mfma_f32_16x16x32_bf16(
                    a[mf], b[nf], acc[mf][nf], 0, 0, 0);
        __syncthreads();
    }

#pragma unroll
    for (int nf = 0; nf < 4; ++nf) {
        const int col = wave * 64 + nf * 16 + l15;
        const float bv = bias[col];
#pragma unroll
        for (int mf = 0; mf < MF; ++mf) {
#pragma unroll
            for (int j = 0; j < 4; ++j) {
                long row = mrow + mf * 16 + l4 * 4 + j;
                C[row * N + col] = acc[mf][nf][j] + bv;
            }
        }
    }
}

// ---------------------------------------------------------------------------
// Sequential scan, register-blocked:
//   thread = (gb = tid>>3 owning outputs g0..g0+3, kb = tid&7 owning 32 ks)
//   W_hh slice 4x32 f32 in registers as float2 (v_pk_fma_f32 path).
//   h in LDS, double-buffered, swizzle-padded (+4 words per 32) so the 8
//   kb offsets land on 8 distinct bank groups.
//   Per step per thread: 8 ds_read_b128 (each feeds 4 outputs), 64 pk-fma,
//   shfl_xor(1,2,4) butterfly reduce, tanh, leak. One barrier per step.
// ---------------------------------------------------------------------------
__global__ __launch_bounds__(512, 2)
void rnn_scan(const float* __restrict__ xp, const float* __restrict__ h0,
              const float* __restrict__ Whh, float* __restrict__ h_all)
{
    __shared__ float hs[2][288];   // 256 + 8*4 pad words per buffer
    const int tid = threadIdx.x;
    const int kb  = tid & 7;       // k-block: k in [kb*32, kb*32+32)
    const int gb  = tid >> 3;      // g-block
    const int g0  = gb * 4;
    const int b   = blockIdx.x;

    // --- W registers: 4 outputs x 32 k, packed as float2 pairs
    f32x2 W2[4][16];
#pragma unroll
    for (int gp = 0; gp < 4; ++gp) {
        const float* wr = Whh + (long)(g0 + gp) * HDIM + kb * 32;
#pragma unroll
        for (int c = 0; c < 8; ++c) {
            f32x4 v = *(const f32x4*)(wr + c * 4);
            W2[gp][2 * c]     = (f32x2){v[0], v[1]};
            W2[gp][2 * c + 1] = (f32x2){v[2], v[3]};
        }
    }

    // --- init h (padded word index = k + (k>>5)*4)
    if (tid < HDIM) {
        float v = h0[(long)b * HDIM + tid];
        hs[0][tid + ((tid >> 5) << 2)] = v;
    }
    // persistent copy of this thread's 4 h values (valid & identical on all kb lanes)
    f32x4 hold = *(const f32x4*)(h0 + (long)b * HDIM + g0);
    __syncthreads();

    const long base = (long)b * TT * HDIM;
    const int  kb9  = kb * 9;            // float4 index of kb*36 padded words
    const int  wIdx = gb + (gb >> 3);    // float4 write index for g0 (padded)

    f32x4 xq = *(const f32x4*)(xp + base + g0);   // t=0 prefetch

    for (int t = 0; t < TT; ++t) {
        const f32x4* hp4 = (const f32x4*)hs[t & 1];

        // prefetch next step's xp (hidden under the FMA burst)
        f32x4 xq_n = xq;
        if (t + 1 < TT)
            xq_n = *(const f32x4*)(xp + base + (long)(t + 1) * HDIM + g0);

        f32x2 acc[4];
#pragma unroll
        for (int gp = 0; gp < 4; ++gp) acc[gp] = (f32x2){0.f, 0.f};

#pragma unroll
        for (int j = 0; j < 8; ++j) {
            f32x4 hv = hp4[kb9 + j];
            f32x2 lo = (f32x2){hv[0], hv[1]};
            f32x2 hi = (f32x2){hv[2], hv[3]};
#pragma unroll
            for (int gp = 0; gp < 4; ++gp) {
                acc[gp] = __builtin_elementwise_fma(W2[gp][2 * j],     lo, acc[gp]);
                acc[gp] = __builtin_elementwise_fma(W2[gp][2 * j + 1], hi, acc[gp]);
            }
        }

        f32x4 hn;
#pragma unroll
        for (int gp = 0; gp < 4; ++gp) {
            float v = acc[gp][0] + acc[gp][1];
            v += __shfl_xor(v, 1);
            v += __shfl_xor(v, 2);
            v += __shfl_xor(v, 4);        // all 8 kb lanes now hold the full sum
            float pre = xq[gp] + v;
            float e   = __expf(2.f * pre);
            float th  = 1.f - 2.f * __builtin_amdgcn_rcpf(1.f + e);
            hn[gp] = 0.9f * hold[gp] + 0.1f * th;
        }
        hold = hn;

        if (kb == 0) {
            ((f32x4*)hs[(t + 1) & 1])[wIdx] = hn;
            *(f32x4*)(h_all + base + (long)t * HDIM + g0) = hn;
        }
        xq = xq_n;
        __syncthreads();   // single barrier per step (double-buffered h)
    }
}

// ---------------------------------------------------------------------------
extern "C" void kernel_launch(void* const* d_in, const int* in_sizes, int n_in,
                              void* d_out, int out_size, void* d_ws, size_t ws_size,
                              hipStream_t stream)
{
    const float* x   = (const float*)d_in[0];
    const float* h0  = (const float*)d_in[1];
    const float* Wxh = (const float*)d_in[2];
    const float* bxh = (const float*)d_in[3];
    const float* Whh = (const float*)d_in[4];
    const float* Why = (const float*)d_in[5];
    const float* bhy = (const float*)d_in[6];

    float* y     = (float*)d_out;                 // (M1, 512)
    float* h_all = y + (long)M1 * ODIM;           // (M1, 256)
    float* xp    = y;   // scratch: xp fits in y region; dead before K3

    gemm_bt<64, 4, HDIM, IDIM><<<M1 / 64, 4 * 64, 0, stream>>>(x, Wxh, bxh, xp);
    rnn_scan<<<BATCH, 512, 0, stream>>>(xp, h0, Whh, h_all);
    gemm_bt<64, 8, ODIM, HDIM><<<M1 / 64, 8 * 64, 0, stream>>>(h_all, Why, bhy, y);
}